// Round 14
// baseline (66.898 us; speedup 1.0000x reference)
//
#include <hip/hip_runtime.h>
#include <math.h>

#define NN 8192
#define IN_F 128
#define OUT_F 64
#define NEG_SLOPE 0.01f
#define K1_ROWS 8    // rows of z per block in k1 -> 1024 blocks
#define CAP 256      // max stored neighbors per row (avg ~33, tail << CAP)

typedef int v4i __attribute__((ext_vector_type(4)));

// Kernel 1: z = X @ W^T + b ; per-row zi = dot(a1,z_i), zj = dot(a2,z_i);
// e_i = exp(lrelu(zi)), d_i = exp(lrelu(zi+zj)). Also zeroes degG.
__global__ __launch_bounds__(256, 4) void k1_linear(
    const float* __restrict__ X, const float* __restrict__ W,
    const float* __restrict__ b, const float* __restrict__ a1,
    const float* __restrict__ a2, float* __restrict__ z,
    float* __restrict__ ev, float* __restrict__ dv, int* __restrict__ degG)
{
    __shared__ float Wl[OUT_F * 129];        // stride 129 -> conflict-free
    __shared__ float xs[K1_ROWS * IN_F];
    const int t = threadIdx.x;
    const int blk = blockIdx.x;

    const int gid = blk * 256 + t;
    if (gid < NN) degG[gid] = 0;

    for (int idx = t; idx < OUT_F * IN_F; idx += 256) {
        int f = idx >> 7, k = idx & 127;
        Wl[f * 129 + k] = W[idx];
    }
    {
        const float4* Xv = reinterpret_cast<const float4*>(X + (size_t)blk * (K1_ROWS * IN_F));
        float4* xsv = reinterpret_cast<float4*>(xs);
        if (t < K1_ROWS * IN_F / 4) xsv[t] = Xv[t];
    }
    __syncthreads();

    const int wid = t >> 6;
    const int lane = t & 63;    // output feature
    const float bias = b[lane];
    const float a1f = a1[lane], a2f = a2[lane];

#pragma unroll
    for (int r2 = 0; r2 < 2; ++r2) {
        const int row = wid * 2 + r2;
        float acc = 0.f;
#pragma unroll 8
        for (int k = 0; k < IN_F; ++k)
            acc = fmaf(xs[row * IN_F + k], Wl[lane * 129 + k], acc);
        const float zval = acc + bias;
        const int i = blk * K1_ROWS + row;
        z[i * OUT_F + lane] = zval;

        float p1 = a1f * zval;
        float p2 = a2f * zval;
#pragma unroll
        for (int off = 32; off > 0; off >>= 1) {
            p1 += __shfl_down(p1, off, 64);
            p2 += __shfl_down(p2, off, 64);
        }
        if (lane == 0) {
            const float s1 = p1;
            const float s2 = p1 + p2;
            const float l1 = s1 > 0.f ? s1 : NEG_SLOPE * s1;
            const float l2 = s2 > 0.f ? s2 : NEG_SLOPE * s2;
            ev[i] = expf(l1);
            dv[i] = expf(l2);
        }
    }
}

// Kernel 2a: PAIRED symmetric stream. Block b reads the upper-triangle
// segments of rows b (cols >= b) and 8191-b (cols >= 8191-b): combined
// length ~8193 cols ~= 32 KB/block -> UNIFORM work, 4096 blocks, 9-deep
// in-flight loads (restores the shape that achieved ~5.7 TB/s on the full
// read, while keeping the byte count halved). Hits append j to row's list;
// hits j>row mirror-append row into j's list (A is symmetric).
__global__ __launch_bounds__(256, 4) void k2a_pair(
    const float* __restrict__ A, int* __restrict__ degG, int* __restrict__ nbrG)
{
    const int b = blockIdx.x;          // 0..4095
    const int rA = b;
    const int rB = NN - 1 - b;
    const int t = threadIdx.x;

    const int sA0 = rA >> 2;           // first int4 containing col rA
    const int sB0 = rB >> 2;
    const int lenA = NN / 4 - sA0;     // int4 count, segment A
    const int lenB = NN / 4 - sB0;
    const int total = lenA + lenB;     // ~2049-2050 (<= 9*256 = 2304)

    const v4i* __restrict__ ArA = reinterpret_cast<const v4i*>(A + (size_t)rA * NN);
    const v4i* __restrict__ ArB = reinterpret_cast<const v4i*>(A + (size_t)rB * NN);

    // Issue up to 9 chunk loads upfront (block-wide 4 KB ascending fronts).
    v4i v[9];
#pragma unroll
    for (int c = 0; c < 9; ++c) {
        const int f = c * 256 + t;
        v4i x = {0, 0, 0, 0};
        if (f < lenA)       x = ArA[sA0 + f];
        else if (f < total) x = ArB[sB0 + (f - lenA)];
        v[c] = x;
    }

#define APPEND(R, J)                                                          \
    {                                                                         \
        int k = atomicAdd(&degG[(R)], 1);                                     \
        if (k < CAP) nbrG[(size_t)(R) * CAP + k] = (J);                       \
        if ((J) > (R)) {                                                      \
            int k2 = atomicAdd(&degG[(J)], 1);                                \
            if (k2 < CAP) nbrG[(size_t)(J) * CAP + k2] = (R);                 \
        }                                                                     \
    }

#pragma unroll
    for (int c = 0; c < 9; ++c) {
        const v4i x = v[c];
        if (((x.x | x.y) | (x.z | x.w)) != 0) {     // rare (~33 hits / 2 rows)
            const int f = c * 256 + t;
            const bool inA = f < lenA;
            const int row = inA ? rA : rB;
            const int j0 = (inA ? (sA0 + f) : (sB0 + (f - lenA))) * 4;
            if (x.x != 0 && j0 + 0 >= row) APPEND(row, j0 + 0)
            if (x.y != 0 && j0 + 1 >= row) APPEND(row, j0 + 1)
            if (x.z != 0 && j0 + 2 >= row) APPEND(row, j0 + 2)
            if (x.w != 0 && j0 + 3 >= row) APPEND(row, j0 + 3)
        }
    }
#undef APPEND
}

// Kernel 2b: gather + finalize (unchanged). One wave per row.
//   S = (deg-1)*e + d ;  out = relu( z_i*(1+(e-d)/S) - (e/S)*sumNbr ).
__global__ __launch_bounds__(256, 8) void k2b_gather(
    const int* __restrict__ degG, const int* __restrict__ nbrG,
    const float* __restrict__ z, const float* __restrict__ ev,
    const float* __restrict__ dv, float* __restrict__ out)
{
    const int t = threadIdx.x;
    const int wid = t >> 6, lane = t & 63;
    const int i = blockIdx.x * 4 + wid;

    const int cnt0 = degG[i];
    const int cnt = cnt0 < CAP ? cnt0 : CAP;
    const int* rowl = nbrG + (size_t)i * CAP;

    float acc = 0.f;
    for (int k0 = 0; k0 < cnt; k0 += 64) {
        const int m = (cnt - k0) < 64 ? (cnt - k0) : 64;
        const int jv = (lane < m) ? rowl[k0 + lane] : 0;
        int kk = 0;
        for (; kk + 4 <= m; kk += 4) {
            const int j0 = __shfl(jv, kk + 0, 64);
            const int j1 = __shfl(jv, kk + 1, 64);
            const int j2 = __shfl(jv, kk + 2, 64);
            const int j3 = __shfl(jv, kk + 3, 64);
            const float z0 = z[(size_t)j0 * OUT_F + lane];
            const float z1 = z[(size_t)j1 * OUT_F + lane];
            const float z2 = z[(size_t)j2 * OUT_F + lane];
            const float z3 = z[(size_t)j3 * OUT_F + lane];
            acc += (z0 + z1) + (z2 + z3);
        }
        for (; kk < m; ++kk) {
            const int j = __shfl(jv, kk, 64);
            acc += z[(size_t)j * OUT_F + lane];
        }
    }

    const float degT = (float)cnt0;
    const float e = ev[i], d = dv[i];
    const float S = (degT - 1.f) * e + d;
    const float zif = z[(size_t)i * OUT_F + lane];
    const float h = zif * (1.f + (e - d) / S) - (e / S) * acc;
    out[(size_t)i * OUT_F + lane] = h > 0.f ? h : 0.f;
}

extern "C" void kernel_launch(void* const* d_in, const int* in_sizes, int n_in,
                              void* d_out, int out_size, void* d_ws, size_t ws_size,
                              hipStream_t stream) {
    const float* X  = (const float*)d_in[0];   // [8192,128]
    const float* A  = (const float*)d_in[1];   // [8192,8192]
    const float* W  = (const float*)d_in[2];   // [64,128]
    const float* b  = (const float*)d_in[3];   // [64]
    const float* a1 = (const float*)d_in[4];   // [64]
    const float* a2 = (const float*)d_in[5];   // [64]
    float* out = (float*)d_out;                // [8192,64]

    char* ws = (char*)d_ws;
    float* z    = (float*)ws;                                   // 2 MB
    float* ev   = (float*)(ws + (size_t)NN * OUT_F * 4);        // 32 KB
    float* dv   = ev + NN;                                      // 32 KB
    int*   degG = (int*)(dv + NN);                              // 32 KB
    int*   nbrG = degG + NN;                                    // 8 MB

    k1_linear<<<NN / K1_ROWS, 256, 0, stream>>>(X, W, b, a1, a2, z, ev, dv, degG);
    k2a_pair<<<NN / 2, 256, 0, stream>>>(A, degG, nbrG);
    k2b_gather<<<NN / 4, 256, 0, stream>>>(degG, nbrG, z, ev, dv, out);
}

// Round 15
// 64.746 us; speedup vs baseline: 1.0332x; 1.0332x over previous
//
#include <hip/hip_runtime.h>
#include <math.h>

#define NN 8192
#define IN_F 128
#define OUT_F 64
#define NEG_SLOPE 0.01f
#define K1_ROWS 8    // rows of z per block in k1 -> 1024 blocks
#define CAP 256      // max stored neighbors per row (avg ~33, tail << CAP)

typedef int v4i __attribute__((ext_vector_type(4)));

// Kernel 1: z = X @ W^T + b ; per-row zi = dot(a1,z_i), zj = dot(a2,z_i);
// e_i = exp(lrelu(zi)), d_i = exp(lrelu(zi+zj)). Also zeroes degG.
__global__ __launch_bounds__(256, 4) void k1_linear(
    const float* __restrict__ X, const float* __restrict__ W,
    const float* __restrict__ b, const float* __restrict__ a1,
    const float* __restrict__ a2, float* __restrict__ z,
    float* __restrict__ ev, float* __restrict__ dv, int* __restrict__ degG)
{
    __shared__ float Wl[OUT_F * 129];        // stride 129 -> conflict-free
    __shared__ float xs[K1_ROWS * IN_F];
    const int t = threadIdx.x;
    const int blk = blockIdx.x;

    const int gid = blk * 256 + t;
    if (gid < NN) degG[gid] = 0;

    for (int idx = t; idx < OUT_F * IN_F; idx += 256) {
        int f = idx >> 7, k = idx & 127;
        Wl[f * 129 + k] = W[idx];
    }
    {
        const float4* Xv = reinterpret_cast<const float4*>(X + (size_t)blk * (K1_ROWS * IN_F));
        float4* xsv = reinterpret_cast<float4*>(xs);
        if (t < K1_ROWS * IN_F / 4) xsv[t] = Xv[t];
    }
    __syncthreads();

    const int wid = t >> 6;
    const int lane = t & 63;    // output feature
    const float bias = b[lane];
    const float a1f = a1[lane], a2f = a2[lane];

#pragma unroll
    for (int r2 = 0; r2 < 2; ++r2) {
        const int row = wid * 2 + r2;
        float acc = 0.f;
#pragma unroll 8
        for (int k = 0; k < IN_F; ++k)
            acc = fmaf(xs[row * IN_F + k], Wl[lane * 129 + k], acc);
        const float zval = acc + bias;
        const int i = blk * K1_ROWS + row;
        z[i * OUT_F + lane] = zval;

        float p1 = a1f * zval;
        float p2 = a2f * zval;
#pragma unroll
        for (int off = 32; off > 0; off >>= 1) {
            p1 += __shfl_down(p1, off, 64);
            p2 += __shfl_down(p2, off, 64);
        }
        if (lane == 0) {
            const float s1 = p1;
            const float s2 = p1 + p2;
            const float l1 = s1 > 0.f ? s1 : NEG_SLOPE * s1;
            const float l2 = s2 > 0.f ? s2 : NEG_SLOPE * s2;
            ev[i] = expf(l1);
            dv[i] = expf(l2);
        }
    }
}

// Kernel 2a: symmetric-halved stream with FULL 8-DEEP pipeline. Block i
// reads row i columns >= i as up to 8 block-wide 4KB fronts, ALL issued
// upfront (slots past the row end masked to zero) -> 8 loads in flight like
// R9, but only upper-triangle bytes (~134 MB total). Hits j>=i append j to
// row i's list; j>i also mirror-appends i into row j's (A symmetric).
__global__ __launch_bounds__(256, 8) void k2a_tri8(
    const float* __restrict__ A, int* __restrict__ degG, int* __restrict__ nbrG)
{
    const int i = blockIdx.x;
    const int t = threadIdx.x;
    const v4i* __restrict__ Arow = reinterpret_cast<const v4i*>(A + (size_t)i * NN);
    const int s0 = i >> 2;              // first int4 containing column i
    // slot c covers int4 index s0 + c*256 + t ; row ends at int4 2047.

    v4i v0 = {0,0,0,0}, v1 = {0,0,0,0}, v2 = {0,0,0,0}, v3 = {0,0,0,0};
    v4i v4_ = {0,0,0,0}, v5 = {0,0,0,0}, v6 = {0,0,0,0}, v7 = {0,0,0,0};
    {
        const int base = s0 + t;
        if (base + 0 * 256 < NN / 4) v0 = Arow[base + 0 * 256];
        if (base + 1 * 256 < NN / 4) v1 = Arow[base + 1 * 256];
        if (base + 2 * 256 < NN / 4) v2 = Arow[base + 2 * 256];
        if (base + 3 * 256 < NN / 4) v3 = Arow[base + 3 * 256];
        if (base + 4 * 256 < NN / 4) v4_ = Arow[base + 4 * 256];
        if (base + 5 * 256 < NN / 4) v5 = Arow[base + 5 * 256];
        if (base + 6 * 256 < NN / 4) v6 = Arow[base + 6 * 256];
        if (base + 7 * 256 < NN / 4) v7 = Arow[base + 7 * 256];
    }

#define APPEND(J)                                                             \
    {                                                                         \
        int k = atomicAdd(&degG[i], 1);                                       \
        if (k < CAP) nbrG[(size_t)i * CAP + k] = (J);                         \
        if ((J) > i) {                                                        \
            int k2 = atomicAdd(&degG[(J)], 1);                                \
            if (k2 < CAP) nbrG[(size_t)(J) * CAP + k2] = i;                   \
        }                                                                     \
    }
#define STEP(C, B)                                                            \
    if (((B.x | B.y) | (B.z | B.w)) != 0) {                                   \
        const int j0 = (s0 + (C) * 256 + t) * 4;                              \
        if (B.x != 0 && j0 + 0 >= i) APPEND(j0 + 0)                           \
        if (B.y != 0 && j0 + 1 >= i) APPEND(j0 + 1)                           \
        if (B.z != 0 && j0 + 2 >= i) APPEND(j0 + 2)                           \
        if (B.w != 0 && j0 + 3 >= i) APPEND(j0 + 3)                           \
    }

    STEP(0, v0) STEP(1, v1) STEP(2, v2) STEP(3, v3)
    STEP(4, v4_) STEP(5, v5) STEP(6, v6) STEP(7, v7)
#undef STEP
#undef APPEND
}

// Kernel 2b: gather + finalize (unchanged). One wave per row.
//   S = (deg-1)*e + d ;  out = relu( z_i*(1+(e-d)/S) - (e/S)*sumNbr ).
__global__ __launch_bounds__(256, 8) void k2b_gather(
    const int* __restrict__ degG, const int* __restrict__ nbrG,
    const float* __restrict__ z, const float* __restrict__ ev,
    const float* __restrict__ dv, float* __restrict__ out)
{
    const int t = threadIdx.x;
    const int wid = t >> 6, lane = t & 63;
    const int i = blockIdx.x * 4 + wid;

    const int cnt0 = degG[i];
    const int cnt = cnt0 < CAP ? cnt0 : CAP;
    const int* rowl = nbrG + (size_t)i * CAP;

    float acc = 0.f;
    for (int k0 = 0; k0 < cnt; k0 += 64) {
        const int m = (cnt - k0) < 64 ? (cnt - k0) : 64;
        const int jv = (lane < m) ? rowl[k0 + lane] : 0;
        int kk = 0;
        for (; kk + 4 <= m; kk += 4) {
            const int j0 = __shfl(jv, kk + 0, 64);
            const int j1 = __shfl(jv, kk + 1, 64);
            const int j2 = __shfl(jv, kk + 2, 64);
            const int j3 = __shfl(jv, kk + 3, 64);
            const float z0 = z[(size_t)j0 * OUT_F + lane];
            const float z1 = z[(size_t)j1 * OUT_F + lane];
            const float z2 = z[(size_t)j2 * OUT_F + lane];
            const float z3 = z[(size_t)j3 * OUT_F + lane];
            acc += (z0 + z1) + (z2 + z3);
        }
        for (; kk < m; ++kk) {
            const int j = __shfl(jv, kk, 64);
            acc += z[(size_t)j * OUT_F + lane];
        }
    }

    const float degT = (float)cnt0;
    const float e = ev[i], d = dv[i];
    const float S = (degT - 1.f) * e + d;
    const float zif = z[(size_t)i * OUT_F + lane];
    const float h = zif * (1.f + (e - d) / S) - (e / S) * acc;
    out[(size_t)i * OUT_F + lane] = h > 0.f ? h : 0.f;
}

extern "C" void kernel_launch(void* const* d_in, const int* in_sizes, int n_in,
                              void* d_out, int out_size, void* d_ws, size_t ws_size,
                              hipStream_t stream) {
    const float* X  = (const float*)d_in[0];   // [8192,128]
    const float* A  = (const float*)d_in[1];   // [8192,8192]
    const float* W  = (const float*)d_in[2];   // [64,128]
    const float* b  = (const float*)d_in[3];   // [64]
    const float* a1 = (const float*)d_in[4];   // [64]
    const float* a2 = (const float*)d_in[5];   // [64]
    float* out = (float*)d_out;                // [8192,64]

    char* ws = (char*)d_ws;
    float* z    = (float*)ws;                                   // 2 MB
    float* ev   = (float*)(ws + (size_t)NN * OUT_F * 4);        // 32 KB
    float* dv   = ev + NN;                                      // 32 KB
    int*   degG = (int*)(dv + NN);                              // 32 KB
    int*   nbrG = degG + NN;                                    // 8 MB

    k1_linear<<<NN / K1_ROWS, 256, 0, stream>>>(X, W, b, a1, a2, z, ev, dv, degG);
    k2a_tri8<<<NN, 256, 0, stream>>>(A, degG, nbrG);
    k2b_gather<<<NN / 4, 256, 0, stream>>>(degG, nbrG, z, ev, dv, out);
}